// Round 4
// baseline (433.657 us; speedup 1.0000x reference)
//
#include <hip/hip_runtime.h>

typedef __bf16 bf16;
typedef __attribute__((ext_vector_type(4))) float   f32x4;
typedef __attribute__((ext_vector_type(4))) __bf16  bf16x4;
typedef __attribute__((ext_vector_type(8))) __bf16  bf16x8;
typedef __attribute__((ext_vector_type(4))) unsigned int u32x4;

#define NB   32
#define SEQ  1024
#define HID  1024
#define HD   128

// ws element offsets (bf16 elements)
#define WT_HI  0ull
#define WT_LO  393216ull
#define Q_HI   786432ull
#define Q_LO   (Q_HI + 4194304ull)
#define K_HI   (Q_HI + 2ull*4194304ull)
#define K_LO   (Q_HI + 3ull*4194304ull)
#define VT_OFF (Q_HI + 4ull*4194304ull)

#define POFF   4194304ull            // probs offset (floats) in d_out
#define SCALE  0.08838834764831845f  // 1/sqrt(128)
#define LOG2E  1.4426950408889634f

#define GLL16(g, l)                                                         \
    __builtin_amdgcn_global_load_lds(                                        \
        (const __attribute__((address_space(1))) void*)(g),                  \
        (__attribute__((address_space(3))) void*)(l), 16, 0, 0)

static __device__ inline void split_f32(float x, bf16& h, bf16& l) {
    h = (bf16)x;
    l = (bf16)(x - (float)h);
}

// ---------------------------------------------------------------------------
// Kernel 0: transpose + hi/lo split of Wq/Wk/Wv -> Wt[z][n(128)][k(1024)]
// ---------------------------------------------------------------------------
__global__ __launch_bounds__(256) void prep_w(const float* __restrict__ Wq,
                                              const float* __restrict__ Wk,
                                              const float* __restrict__ Wv,
                                              bf16* __restrict__ ws) {
    __shared__ bf16 Th[128 * 72];
    __shared__ bf16 Tl[128 * 72];
    int z  = blockIdx.x >> 4;
    int kt = blockIdx.x & 15;
    const float* W = (z == 0) ? Wq : ((z == 1) ? Wk : Wv);
    int t = threadIdx.x;

    for (int i = 0; i < 8; ++i) {
        int idx = (i * 256 + t) * 4;
        int kl  = idx >> 7;          // 0..63
        int n   = idx & 127;
        f32x4 v = *(const f32x4*)(W + (size_t)(kt * 64 + kl) * 128 + n);
        for (int j = 0; j < 4; ++j) {
            bf16 h, lo; split_f32(v[j], h, lo);
            Th[(n + j) * 72 + kl] = h;
            Tl[(n + j) * 72 + kl] = lo;
        }
    }
    __syncthreads();
    for (int i = 0; i < 4; ++i) {
        int idx = (i * 256 + t) * 8;
        int n   = idx >> 6;
        int kl  = idx & 63;
        bf16x8 vh = *(const bf16x8*)(Th + n * 72 + kl);
        bf16x8 vl = *(const bf16x8*)(Tl + n * 72 + kl);
        size_t o = (size_t)z * 131072 + (size_t)n * 1024 + kt * 64 + kl;
        *(bf16x8*)(ws + WT_HI + o) = vh;
        *(bf16x8*)(ws + WT_LO + o) = vl;
    }
}

// ---------------------------------------------------------------------------
// Kernel 1: Q/K/V = X @ W + b  (bf16x2 emulated fp32 via 3 MFMAs)
// T3 2-phase pipeline: double-buffered 32 KB staging (64 KB LDS total).
// Iteration kb issues kb+1's global_load_lds BEFORE computing kb, so the
// barrier's vmcnt(0) drain waits on loads that already flew under
// ~500+ cycles of ds_read + split-VALU + 48 MFMAs. One barrier per
// iteration (was two + fully-exposed latency).
// XCD swizzle kept from r3 (z-siblings share an XCD's L2 for X).
// ---------------------------------------------------------------------------
__global__ __launch_bounds__(256) void qkv_gemm(const float* __restrict__ X,
                                                const float* __restrict__ bq,
                                                const float* __restrict__ bk,
                                                const float* __restrict__ bv,
                                                bf16* __restrict__ ws) {
    __shared__ __align__(16) char smem_raw[65536];
    // buffer b (b=0,1) at smem_raw + b*32768:
    //   Xf: 16384 B (128x32 fp32, block-swizzled)
    //   Bh:  8192 B (128x32 bf16)   at +16384
    //   Bl:  8192 B                 at +24576
    bf16* Ep = (bf16*)smem_raw;                   // epilogue 128x136 bf16 (34816 B)

    // xcd = bx % 8 (HW round-robin); mt in [32*xcd, 32*xcd+32), z = 0..2
    int xcd    = blockIdx.x & 7;
    int slot   = blockIdx.x >> 3;          // 0..95
    int z      = slot >> 5;                // 0..2
    int mt_blk = xcd * 32 + (slot & 31);   // 0..255
    int t  = threadIdx.x;
    int w  = t >> 6;
    int l  = t & 63;
    int lm = l & 15;
    int q  = l >> 4;
    int mwb = (w & 1) * 64;
    int nwb = (w >> 1) * 64;

    const bf16* wth = ws + WT_HI + (size_t)z * 131072;
    const bf16* wtl = ws + WT_LO + (size_t)z * 131072;

    int srowA = w * 32 + (l >> 3);
    int scolA = ((l & 7) ^ (l >> 3)) * 4;          // floats
    const float* gA = X + (size_t)(mt_blk * 128 + srowA) * 1024 + scolA;
    int lbaseA = (w * 32) * 32;                     // floats, wave-uniform

    int srowB = w * 32 + (l >> 2);
    int scolB = ((l & 3) ^ ((l >> 3) & 3)) * 8;
    const bf16* gBh = wth + (size_t)srowB * 1024 + scolB;
    const bf16* gBl = wtl + (size_t)srowB * 1024 + scolB;
    int lbase0 = (w * 32) * 32;
    int lbase1 = (w * 32 + 16) * 32;

    int fcol = (q ^ ((lm >> 1) & 3)) * 8;          // B frag swizzle
    int e7   = lm & 7;                              // A frag swizzle key

    f32x4 acc[4][4] = {};

    // ---- prologue: stage kb=0 into buffer 0
    {
        float* Xf0 = (float*)smem_raw;
        bf16*  Bh0 = (bf16*)(smem_raw + 16384);
        bf16*  Bl0 = (bf16*)(smem_raw + 24576);
        GLL16(gA,          Xf0 + lbaseA);
        GLL16(gA + 8192,   Xf0 + lbaseA + 8 * 32);
        GLL16(gA + 16384,  Xf0 + lbaseA + 16 * 32);
        GLL16(gA + 24576,  Xf0 + lbaseA + 24 * 32);
        GLL16(gBh,           Bh0 + lbase0);
        GLL16(gBh + 16384,   Bh0 + lbase1);
        GLL16(gBl,           Bl0 + lbase0);
        GLL16(gBl + 16384,   Bl0 + lbase1);
    }
    __syncthreads();   // drains vmcnt: buffer 0 staged

    for (int kb = 0; kb < 32; ++kb) {
        char* cbuf = smem_raw + (size_t)(kb & 1) * 32768;
        float* Xf = (float*)cbuf;
        bf16*  Bh = (bf16*)(cbuf + 16384);
        bf16*  Bl = (bf16*)(cbuf + 24576);

        // stage kb+1 into the other buffer (loads fly under the compute below)
        if (kb < 31) {
            char* nbuf = smem_raw + (size_t)((kb + 1) & 1) * 32768;
            float* Xn = (float*)nbuf;
            bf16*  Bhn = (bf16*)(nbuf + 16384);
            bf16*  Bln = (bf16*)(nbuf + 24576);
            int go = (kb + 1) * 32;
            GLL16(gA + go,          Xn + lbaseA);
            GLL16(gA + go + 8192,   Xn + lbaseA + 8 * 32);
            GLL16(gA + go + 16384,  Xn + lbaseA + 16 * 32);
            GLL16(gA + go + 24576,  Xn + lbaseA + 24 * 32);
            GLL16(gBh + go,           Bhn + lbase0);
            GLL16(gBh + go + 16384,   Bhn + lbase1);
            GLL16(gBl + go,           Bln + lbase0);
            GLL16(gBl + go + 16384,   Bln + lbase1);
        }

        bf16x8 ah[4], al[4], bh[4], bl[4];
        for (int mt = 0; mt < 4; ++mt) {
            int row = mwb + mt * 16 + lm;
            f32x4 v0 = *(const f32x4*)(Xf + row * 32 + ((2 * q)     ^ e7) * 4);
            f32x4 v1 = *(const f32x4*)(Xf + row * 32 + ((2 * q + 1) ^ e7) * 4);
            bf16x8 h, lo;
            for (int j = 0; j < 4; ++j) {
                bf16 hh, ll;
                split_f32(v0[j], hh, ll); h[j] = hh;     lo[j] = ll;
                split_f32(v1[j], hh, ll); h[4 + j] = hh; lo[4 + j] = ll;
            }
            ah[mt] = h; al[mt] = lo;
        }
        for (int nt = 0; nt < 4; ++nt) {
            int row = nwb + nt * 16 + lm;
            bh[nt] = *(const bf16x8*)(Bh + row * 32 + fcol);
            bl[nt] = *(const bf16x8*)(Bl + row * 32 + fcol);
        }
        for (int mt = 0; mt < 4; ++mt)
            for (int nt = 0; nt < 4; ++nt) {
                acc[mt][nt] = __builtin_amdgcn_mfma_f32_16x16x32_bf16(ah[mt], bh[nt], acc[mt][nt], 0, 0, 0);
                acc[mt][nt] = __builtin_amdgcn_mfma_f32_16x16x32_bf16(ah[mt], bl[nt], acc[mt][nt], 0, 0, 0);
                acc[mt][nt] = __builtin_amdgcn_mfma_f32_16x16x32_bf16(al[mt], bh[nt], acc[mt][nt], 0, 0, 0);
            }

        // one barrier per iter: drains this wave's vmcnt (next buffer staged)
        // and guarantees all waves finished reading cbuf before it's restaged
        __syncthreads();
    }

    const float* bias = (z == 0) ? bq : ((z == 1) ? bk : bv);
    float scale = (z == 0) ? SCALE : 1.0f;

    if (z < 2) {
        bf16* dh = ws + ((z == 0) ? Q_HI : K_HI);
        bf16* dl = ws + ((z == 0) ? Q_LO : K_LO);
        for (int mt = 0; mt < 4; ++mt)
            for (int nt = 0; nt < 4; ++nt)
                for (int r = 0; r < 4; ++r) {
                    int row = mwb + mt * 16 + q * 4 + r;
                    int col = nwb + nt * 16 + lm;
                    float v = (acc[mt][nt][r] + bias[col]) * scale;
                    Ep[row * 136 + col] = (bf16)v;
                }
        __syncthreads();
        for (int i = 0; i < 8; ++i) {
            int idx = i * 2048 + t * 8;
            int row = idx >> 7, col = idx & 127;
            bf16x8 vv = *(const bf16x8*)(Ep + row * 136 + col);
            *(bf16x8*)(dh + ((size_t)(mt_blk * 128 + row)) * 128 + col) = vv;
        }
        __syncthreads();
        for (int mt = 0; mt < 4; ++mt)
            for (int nt = 0; nt < 4; ++nt)
                for (int r = 0; r < 4; ++r) {
                    int row = mwb + mt * 16 + q * 4 + r;
                    int col = nwb + nt * 16 + lm;
                    float v = (acc[mt][nt][r] + bias[col]) * scale;
                    bf16 h = (bf16)v;
                    Ep[row * 136 + col] = (bf16)(v - (float)h);
                }
        __syncthreads();
        for (int i = 0; i < 8; ++i) {
            int idx = i * 2048 + t * 8;
            int row = idx >> 7, col = idx & 127;
            bf16x8 vv = *(const bf16x8*)(Ep + row * 136 + col);
            *(bf16x8*)(dl + ((size_t)(mt_blk * 128 + row)) * 128 + col) = vv;
        }
    } else {
        bf16* vt = ws + VT_OFF;
        size_t b  = mt_blk >> 3;
        int   sb  = (mt_blk & 7) * 128;
        for (int mt = 0; mt < 4; ++mt)
            for (int nt = 0; nt < 4; ++nt)
                for (int r = 0; r < 4; ++r) {
                    int row = mwb + mt * 16 + q * 4 + r;   // s within tile
                    int col = nwb + nt * 16 + lm;          // d
                    float v = acc[mt][nt][r] + bias[col];
                    Ep[col * 136 + row] = (bf16)v;
                }
        __syncthreads();
        for (int i = 0; i < 8; ++i) {
            int idx = i * 2048 + t * 8;
            int d = idx >> 7, s8 = idx & 127;
            bf16x8 vv = *(const bf16x8*)(Ep + d * 136 + s8);
            *(bf16x8*)(vt + b * 131072 + (size_t)d * 1024 + sb + s8) = vv;
        }
    }
}

// ---------------------------------------------------------------------------
// Kernel 2: fused scores + softmax + probs-store + PV — identical to r3
// (XCD swizzle: 4 batches pinned per XCD; body = verified 64-VGPR codegen)
// ---------------------------------------------------------------------------
__global__ __launch_bounds__(512, 4) void attn_fused(const bf16* __restrict__ ws,
                                                     float* __restrict__ out) {
    __shared__ __align__(16) bf16 sm[16512];   // Qh/Ql (8704 el) then P 32x516
    __shared__ float red[8][32];
    __shared__ float rstat[32];
    bf16* Qh = sm;
    bf16* Ql = sm + 4352;
    bf16* P  = sm;

    // xcd = bx % 8; batches 4*xcd..4*xcd+3 pinned to this XCD
    int xcd  = blockIdx.x & 7;
    int slot = blockIdx.x >> 3;          // 0..127
    int bb   = xcd * 4 + (slot >> 5);    // 0..31
    int mq   = slot & 31;                // 0..31
    int t  = threadIdx.x;
    int w  = t >> 6;
    int l  = t & 63;
    int lm = l & 15;
    int q  = l >> 4;

    const bf16* qhp = ws + Q_HI + ((size_t)bb * 1024 + mq * 32) * 128;
    const bf16* qlp = ws + Q_LO + ((size_t)bb * 1024 + mq * 32) * 128;
    {
        int row = t >> 4;
        int k8  = (t & 15) * 8;
        *(u32x4*)(Qh + row * 136 + k8) = *(const u32x4*)(qhp + (size_t)row * 128 + k8);
        *(u32x4*)(Ql + row * 136 + k8) = *(const u32x4*)(qlp + (size_t)row * 128 + k8);
    }
    __syncthreads();

    const bf16* khp = ws + K_HI + (size_t)bb * 131072;
    const bf16* klp = ws + K_LO + (size_t)bb * 131072;

    f32x4 acc[2][8] = {};
    for (int kc = 0; kc < 4; ++kc) {
        bf16x8 ah[2], al[2];
        for (int mt = 0; mt < 2; ++mt) {
            int row = mt * 16 + lm;
            ah[mt] = *(const bf16x8*)(Qh + row * 136 + kc * 32 + q * 8);
            al[mt] = *(const bf16x8*)(Ql + row * 136 + kc * 32 + q * 8);
        }
        size_t kb0 = (size_t)(w * 128 + lm) * 128 + kc * 32 + q * 8;
        bf16x8 pbh = *(const bf16x8*)(khp + kb0);
        bf16x8 pbl = *(const bf16x8*)(klp + kb0);
        for (int nt = 0; nt < 8; ++nt) {
            bf16x8 cbh = pbh, cbl = pbl;
            if (nt < 7) {
                size_t kb = kb0 + (size_t)(nt + 1) * 16 * 128;
                pbh = *(const bf16x8*)(khp + kb);
                pbl = *(const bf16x8*)(klp + kb);
            }
            for (int mt = 0; mt < 2; ++mt) {
                acc[mt][nt] = __builtin_amdgcn_mfma_f32_16x16x32_bf16(ah[mt], cbh, acc[mt][nt], 0, 0, 0);
                acc[mt][nt] = __builtin_amdgcn_mfma_f32_16x16x32_bf16(ah[mt], cbl, acc[mt][nt], 0, 0, 0);
                acc[mt][nt] = __builtin_amdgcn_mfma_f32_16x16x32_bf16(al[mt], cbh, acc[mt][nt], 0, 0, 0);
            }
        }
    }

    // ---- row max
    for (int mt = 0; mt < 2; ++mt)
        for (int r = 0; r < 4; ++r) {
            float m = acc[mt][0][r];
            for (int nt = 1; nt < 8; ++nt) m = fmaxf(m, acc[mt][nt][r]);
            m = fmaxf(m, __shfl_xor(m, 1));
            m = fmaxf(m, __shfl_xor(m, 2));
            m = fmaxf(m, __shfl_xor(m, 4));
            m = fmaxf(m, __shfl_xor(m, 8));
            if (lm == 0) red[w][mt * 16 + q * 4 + r] = m;
        }
    __syncthreads();
    if (t < 32) {
        float m = red[0][t];
        for (int ww = 1; ww < 8; ++ww) m = fmaxf(m, red[ww][t]);
        rstat[t] = m;
    }
    __syncthreads();

    // ---- exp + row sum
    for (int mt = 0; mt < 2; ++mt)
        for (int r = 0; r < 4; ++r) {
            float rm = rstat[mt * 16 + q * 4 + r];
            float s = 0.f;
            for (int nt = 0; nt < 8; ++nt) {
                float e = exp2f((acc[mt][nt][r] - rm) * LOG2E);
                acc[mt][nt][r] = e;
                s += e;
            }
            s += __shfl_xor(s, 1);
            s += __shfl_xor(s, 2);
            s += __shfl_xor(s, 4);
            s += __shfl_xor(s, 8);
            if (lm == 0) red[w][mt * 16 + q * 4 + r] = s;
        }
    __syncthreads();
    if (t < 32) {
        float s = 0.f;
        for (int ww = 0; ww < 8; ++ww) s += red[ww][t];
        rstat[t] = 1.0f / s;
    }
    __syncthreads();

    // ---- normalize fully in registers (no global store here)
    for (int mt = 0; mt < 2; ++mt)
        for (int r = 0; r < 4; ++r) {
            float inv = rstat[mt * 16 + q * 4 + r];
            for (int nt = 0; nt < 8; ++nt)
                acc[mt][nt][r] *= inv;
        }
    __syncthreads();   // Q-region LDS dead; safe to overlay P

    // ---- PV: 2 phases, wave-private d-tile (d = 16w + lm)
    //      probs stores interleaved into each phase; barriers drain LDS only
    const bf16* vt = ws + VT_OFF + (size_t)bb * 131072;
    float* pout = out + POFF + (size_t)bb * 1048576;
    f32x4 acco[2] = {};
    for (int g = 0; g < 2; ++g) {
        if ((w >> 2) == g) {
            int colb = (w & 3) * 128;
            for (int mt = 0; mt < 2; ++mt)
                for (int nt = 0; nt < 8; ++nt)
                    for (int r = 0; r < 4; ++r) {
                        int row = mt * 16 + 4 * q + r;
                        int col = colb + nt * 16 + lm;
                        P[row * 516 + col] = (bf16)acc[mt][nt][r];
                    }
        }
        // fire-and-forget fp32 probs stores for this phase's nt half;
        // they drain under the V loads + MFMAs below (vmcnt never hit 0 here)
        for (int mt = 0; mt < 2; ++mt)
            for (int r = 0; r < 4; ++r) {
                int row = mq * 32 + mt * 16 + q * 4 + r;
                float* pr = pout + (size_t)row * 1024 + w * 128 + lm;
                for (int nt = 4 * g; nt < 4 * g + 4; ++nt)
                    pr[nt * 16] = acc[mt][nt][r];
            }

        __builtin_amdgcn_sched_barrier(0);
        asm volatile("s_waitcnt lgkmcnt(0)" ::: "memory");
        __builtin_amdgcn_s_barrier();
        __builtin_amdgcn_sched_barrier(0);

        for (int c2 = 0; c2 < 16; ++c2) {
            bf16x8 vb = *(const bf16x8*)(vt + (size_t)(w * 16 + lm) * 1024 + g * 512 + c2 * 32 + q * 8);
            for (int mt = 0; mt < 2; ++mt) {
                bf16x8 ap = *(const bf16x8*)(P + (mt * 16 + lm) * 516 + c2 * 32 + q * 8);
                acco[mt] = __builtin_amdgcn_mfma_f32_16x16x32_bf16(ap, vb, acco[mt], 0, 0, 0);
            }
        }

        __builtin_amdgcn_sched_barrier(0);
        asm volatile("s_waitcnt lgkmcnt(0)" ::: "memory");
        __builtin_amdgcn_s_barrier();
        __builtin_amdgcn_sched_barrier(0);
    }

    // ---- store out: C-layout, d = 16w + lm
    for (int mt = 0; mt < 2; ++mt)
        for (int r = 0; r < 4; ++r) {
            int row = mq * 32 + mt * 16 + 4 * q + r;
            out[((size_t)bb * 1024 + row) * 128 + w * 16 + lm] = acco[mt][r];
        }
}

// ---------------------------------------------------------------------------
extern "C" void kernel_launch(void* const* d_in, const int* in_sizes, int n_in,
                              void* d_out, int out_size, void* d_ws, size_t ws_size,
                              hipStream_t stream) {
    const float* X  = (const float*)d_in[0];
    const float* Wq = (const float*)d_in[1];
    const float* bq = (const float*)d_in[2];
    const float* Wk = (const float*)d_in[3];
    const float* bk = (const float*)d_in[4];
    const float* Wv = (const float*)d_in[5];
    const float* bv = (const float*)d_in[6];
    float* out = (float*)d_out;
    bf16* ws   = (bf16*)d_ws;

    prep_w<<<48, 256, 0, stream>>>(Wq, Wk, Wv, ws);
    qkv_gemm<<<768, 256, 0, stream>>>(X, bq, bk, bv, ws);
    attn_fused<<<1024, 512, 0, stream>>>(ws, out);
}

// Round 6
// 399.873 us; speedup vs baseline: 1.0845x; 1.0845x over previous
//
#include <hip/hip_runtime.h>

typedef __bf16 bf16;
typedef __attribute__((ext_vector_type(4))) float   f32x4;
typedef __attribute__((ext_vector_type(4))) __bf16  bf16x4;
typedef __attribute__((ext_vector_type(8))) __bf16  bf16x8;
typedef __attribute__((ext_vector_type(4))) unsigned int u32x4;

#define NB   32
#define SEQ  1024
#define HID  1024
#define HD   128

// ws element offsets (bf16 elements)
#define WT_HI  0ull
#define WT_LO  393216ull
#define Q_HI   786432ull
#define Q_LO   (Q_HI + 4194304ull)
#define K_HI   (Q_HI + 2ull*4194304ull)
#define K_LO   (Q_HI + 3ull*4194304ull)
#define VT_OFF (Q_HI + 4ull*4194304ull)

#define POFF   4194304ull            // probs offset (floats) in d_out
#define SCALE  0.08838834764831845f  // 1/sqrt(128)
#define LOG2E  1.4426950408889634f

#define GLL16(g, l)                                                         \
    __builtin_amdgcn_global_load_lds(                                        \
        (const __attribute__((address_space(1))) void*)(g),                  \
        (__attribute__((address_space(3))) void*)(l), 16, 0, 0)

static __device__ inline void split_f32(float x, bf16& h, bf16& l) {
    h = (bf16)x;
    l = (bf16)(x - (float)h);
}

// ---------------------------------------------------------------------------
// Kernel 0: transpose + hi/lo split of Wq/Wk/Wv -> Wt[z][n(128)][k(1024)]
// ---------------------------------------------------------------------------
__global__ __launch_bounds__(256) void prep_w(const float* __restrict__ Wq,
                                              const float* __restrict__ Wk,
                                              const float* __restrict__ Wv,
                                              bf16* __restrict__ ws) {
    __shared__ bf16 Th[128 * 72];
    __shared__ bf16 Tl[128 * 72];
    int z  = blockIdx.x >> 4;
    int kt = blockIdx.x & 15;
    const float* W = (z == 0) ? Wq : ((z == 1) ? Wk : Wv);
    int t = threadIdx.x;

    for (int i = 0; i < 8; ++i) {
        int idx = (i * 256 + t) * 4;
        int kl  = idx >> 7;          // 0..63
        int n   = idx & 127;
        f32x4 v = *(const f32x4*)(W + (size_t)(kt * 64 + kl) * 128 + n);
        for (int j = 0; j < 4; ++j) {
            bf16 h, lo; split_f32(v[j], h, lo);
            Th[(n + j) * 72 + kl] = h;
            Tl[(n + j) * 72 + kl] = lo;
        }
    }
    __syncthreads();
    for (int i = 0; i < 4; ++i) {
        int idx = (i * 256 + t) * 8;
        int n   = idx >> 6;
        int kl  = idx & 63;
        bf16x8 vh = *(const bf16x8*)(Th + n * 72 + kl);
        bf16x8 vl = *(const bf16x8*)(Tl + n * 72 + kl);
        size_t o = (size_t)z * 131072 + (size_t)n * 1024 + kt * 64 + kl;
        *(bf16x8*)(ws + WT_HI + o) = vh;
        *(bf16x8*)(ws + WT_LO + o) = vl;
    }
}

// ---------------------------------------------------------------------------
// Kernel 1: Q/K/V = X @ W + b  (bf16x2 emulated fp32 via 3 MFMAs) — r4 version
// ---------------------------------------------------------------------------
__global__ __launch_bounds__(256) void qkv_gemm(const float* __restrict__ X,
                                                const float* __restrict__ bq,
                                                const float* __restrict__ bk,
                                                const float* __restrict__ bv,
                                                bf16* __restrict__ ws) {
    __shared__ __align__(16) char smem_raw[65536];
    bf16* Ep = (bf16*)smem_raw;                   // epilogue 128x136 bf16

    int xcd    = blockIdx.x & 7;
    int slot   = blockIdx.x >> 3;          // 0..95
    int z      = slot >> 5;                // 0..2
    int mt_blk = xcd * 32 + (slot & 31);   // 0..255
    int t  = threadIdx.x;
    int w  = t >> 6;
    int l  = t & 63;
    int lm = l & 15;
    int q  = l >> 4;
    int mwb = (w & 1) * 64;
    int nwb = (w >> 1) * 64;

    const bf16* wth = ws + WT_HI + (size_t)z * 131072;
    const bf16* wtl = ws + WT_LO + (size_t)z * 131072;

    int srowA = w * 32 + (l >> 3);
    int scolA = ((l & 7) ^ (l >> 3)) * 4;          // floats
    const float* gA = X + (size_t)(mt_blk * 128 + srowA) * 1024 + scolA;
    int lbaseA = (w * 32) * 32;                     // floats, wave-uniform

    int srowB = w * 32 + (l >> 2);
    int scolB = ((l & 3) ^ ((l >> 3) & 3)) * 8;
    const bf16* gBh = wth + (size_t)srowB * 1024 + scolB;
    const bf16* gBl = wtl + (size_t)srowB * 1024 + scolB;
    int lbase0 = (w * 32) * 32;
    int lbase1 = (w * 32 + 16) * 32;

    int fcol = (q ^ ((lm >> 1) & 3)) * 8;          // B frag swizzle
    int e7   = lm & 7;                              // A frag swizzle key

    f32x4 acc[4][4] = {};

    {
        float* Xf0 = (float*)smem_raw;
        bf16*  Bh0 = (bf16*)(smem_raw + 16384);
        bf16*  Bl0 = (bf16*)(smem_raw + 24576);
        GLL16(gA,          Xf0 + lbaseA);
        GLL16(gA + 8192,   Xf0 + lbaseA + 8 * 32);
        GLL16(gA + 16384,  Xf0 + lbaseA + 16 * 32);
        GLL16(gA + 24576,  Xf0 + lbaseA + 24 * 32);
        GLL16(gBh,           Bh0 + lbase0);
        GLL16(gBh + 16384,   Bh0 + lbase1);
        GLL16(gBl,           Bl0 + lbase0);
        GLL16(gBl + 16384,   Bl0 + lbase1);
    }
    __syncthreads();

    for (int kb = 0; kb < 32; ++kb) {
        char* cbuf = smem_raw + (size_t)(kb & 1) * 32768;
        float* Xf = (float*)cbuf;
        bf16*  Bh = (bf16*)(cbuf + 16384);
        bf16*  Bl = (bf16*)(cbuf + 24576);

        if (kb < 31) {
            char* nbuf = smem_raw + (size_t)((kb + 1) & 1) * 32768;
            float* Xn = (float*)nbuf;
            bf16*  Bhn = (bf16*)(nbuf + 16384);
            bf16*  Bln = (bf16*)(nbuf + 24576);
            int go = (kb + 1) * 32;
            GLL16(gA + go,          Xn + lbaseA);
            GLL16(gA + go + 8192,   Xn + lbaseA + 8 * 32);
            GLL16(gA + go + 16384,  Xn + lbaseA + 16 * 32);
            GLL16(gA + go + 24576,  Xn + lbaseA + 24 * 32);
            GLL16(gBh + go,           Bhn + lbase0);
            GLL16(gBh + go + 16384,   Bhn + lbase1);
            GLL16(gBl + go,           Bln + lbase0);
            GLL16(gBl + go + 16384,   Bln + lbase1);
        }

        bf16x8 ah[4], al[4], bh[4], bl[4];
        for (int mt = 0; mt < 4; ++mt) {
            int row = mwb + mt * 16 + lm;
            f32x4 v0 = *(const f32x4*)(Xf + row * 32 + ((2 * q)     ^ e7) * 4);
            f32x4 v1 = *(const f32x4*)(Xf + row * 32 + ((2 * q + 1) ^ e7) * 4);
            bf16x8 h, lo;
            for (int j = 0; j < 4; ++j) {
                bf16 hh, ll;
                split_f32(v0[j], hh, ll); h[j] = hh;     lo[j] = ll;
                split_f32(v1[j], hh, ll); h[4 + j] = hh; lo[4 + j] = ll;
            }
            ah[mt] = h; al[mt] = lo;
        }
        for (int nt = 0; nt < 4; ++nt) {
            int row = nwb + nt * 16 + lm;
            bh[nt] = *(const bf16x8*)(Bh + row * 32 + fcol);
            bl[nt] = *(const bf16x8*)(Bl + row * 32 + fcol);
        }
        for (int mt = 0; mt < 4; ++mt)
            for (int nt = 0; nt < 4; ++nt) {
                acc[mt][nt] = __builtin_amdgcn_mfma_f32_16x16x32_bf16(ah[mt], bh[nt], acc[mt][nt], 0, 0, 0);
                acc[mt][nt] = __builtin_amdgcn_mfma_f32_16x16x32_bf16(ah[mt], bl[nt], acc[mt][nt], 0, 0, 0);
                acc[mt][nt] = __builtin_amdgcn_mfma_f32_16x16x32_bf16(al[mt], bh[nt], acc[mt][nt], 0, 0, 0);
            }

        __syncthreads();
    }

    const float* bias = (z == 0) ? bq : ((z == 1) ? bk : bv);
    float scale = (z == 0) ? SCALE : 1.0f;

    if (z < 2) {
        bf16* dh = ws + ((z == 0) ? Q_HI : K_HI);
        bf16* dl = ws + ((z == 0) ? Q_LO : K_LO);
        for (int mt = 0; mt < 4; ++mt)
            for (int nt = 0; nt < 4; ++nt)
                for (int r = 0; r < 4; ++r) {
                    int row = mwb + mt * 16 + q * 4 + r;
                    int col = nwb + nt * 16 + lm;
                    float v = (acc[mt][nt][r] + bias[col]) * scale;
                    Ep[row * 136 + col] = (bf16)v;
                }
        __syncthreads();
        for (int i = 0; i < 8; ++i) {
            int idx = i * 2048 + t * 8;
            int row = idx >> 7, col = idx & 127;
            bf16x8 vv = *(const bf16x8*)(Ep + row * 136 + col);
            *(bf16x8*)(dh + ((size_t)(mt_blk * 128 + row)) * 128 + col) = vv;
        }
        __syncthreads();
        for (int mt = 0; mt < 4; ++mt)
            for (int nt = 0; nt < 4; ++nt)
                for (int r = 0; r < 4; ++r) {
                    int row = mwb + mt * 16 + q * 4 + r;
                    int col = nwb + nt * 16 + lm;
                    float v = (acc[mt][nt][r] + bias[col]) * scale;
                    bf16 h = (bf16)v;
                    Ep[row * 136 + col] = (bf16)(v - (float)h);
                }
        __syncthreads();
        for (int i = 0; i < 8; ++i) {
            int idx = i * 2048 + t * 8;
            int row = idx >> 7, col = idx & 127;
            bf16x8 vv = *(const bf16x8*)(Ep + row * 136 + col);
            *(bf16x8*)(dl + ((size_t)(mt_blk * 128 + row)) * 128 + col) = vv;
        }
    } else {
        bf16* vt = ws + VT_OFF;
        size_t b  = mt_blk >> 3;
        int   sb  = (mt_blk & 7) * 128;
        for (int mt = 0; mt < 4; ++mt)
            for (int nt = 0; nt < 4; ++nt)
                for (int r = 0; r < 4; ++r) {
                    int row = mwb + mt * 16 + q * 4 + r;   // s within tile
                    int col = nwb + nt * 16 + lm;          // d
                    float v = acc[mt][nt][r] + bias[col];
                    Ep[col * 136 + row] = (bf16)v;
                }
        __syncthreads();
        for (int i = 0; i < 8; ++i) {
            int idx = i * 2048 + t * 8;
            int d = idx >> 7, s8 = idx & 127;
            bf16x8 vv = *(const bf16x8*)(Ep + d * 136 + s8);
            *(bf16x8*)(vt + b * 131072 + (size_t)d * 1024 + sb + s8) = vv;
        }
    }
}

// ---------------------------------------------------------------------------
// Kernel 2: fused scores + softmax + probs-store + PV — cooperative staging
// QK: waves relabeled (mt = w&1 row-tile, kt4 = w>>1 key subtile); each
//     128-key x 32-hd chunk is staged block-cooperatively via
//     global_load_lds into a 3-buffer ring, counted vmcnt(2), depth-2
//     prefetch, one raw barrier per step. In-flight loads cost 0 VGPRs.
// PV: V slices staged the same way (3 x 8KB ring, vmcnt(1)).
// Probs fp32 stores at kernel tail (keeps vmcnt counting clean).
// Numerics identical to r2-r4 (same MFMA decomposition + order).
// LDS arena 67.7 KB -> 2 blocks/CU; launch_bounds pins <=128 regs/wave.
// ---------------------------------------------------------------------------
__global__ __launch_bounds__(512, 4) void attn_fused(const bf16* __restrict__ ws,
                                                     float* __restrict__ out) {
    // arena (bf16 el): QK: K-ring 3x8192 el at [0,24576), Q at [24576,33280)
    //                  PV: P 32x516 at [0,16512), V-ring 3x4096 at [16512,28800)
    __shared__ __align__(16) bf16 arena[33280];
    __shared__ float red[8][32];
    __shared__ float rstat[32];

    int xcd  = blockIdx.x & 7;
    int slot = blockIdx.x >> 3;          // 0..127
    int bb   = xcd * 4 + (slot >> 5);    // 0..31
    int mq   = slot & 31;                // 0..31
    int t  = threadIdx.x;
    int w  = t >> 6;
    int l  = t & 63;
    int lm = l & 15;
    int q  = l >> 4;
    int mt  = w & 1;    // row-tile: rows mt*16..+16
    int kt4 = w >> 1;   // key subtile within chunk: keys kt4*32..+32

    const bf16* khp = ws + K_HI + (size_t)bb * 131072;
    const bf16* klp = ws + K_LO + (size_t)bb * 131072;
    // per-lane staging sources (lane l covers key w*16 + l/4, 8 cols at (l&3)*8)
    const bf16* gkh = khp + (size_t)(w * 16 + (l >> 2)) * 128 + (l & 3) * 8;
    const bf16* gkl = klp + (size_t)(w * 16 + (l >> 2)) * 128 + (l & 3) * 8;

    bf16* Qh = arena + 24576;
    bf16* Ql = arena + 24576 + 4352;

#define KSTAGE(s)                                                              \
    do {                                                                       \
        GLL16(gkh + ((s) & 7) * 16384 + ((s) >> 3) * 32,                       \
              arena + ((s) % 3) * 8192 + w * 512);                             \
        GLL16(gkl + ((s) & 7) * 16384 + ((s) >> 3) * 32,                       \
              arena + ((s) % 3) * 8192 + 4096 + w * 512);                      \
    } while (0)

    // prologue: start K pipeline, then stage Q
    KSTAGE(0);
    KSTAGE(1);
    {
        const bf16* qhp = ws + Q_HI + ((size_t)bb * 1024 + mq * 32) * 128;
        const bf16* qlp = ws + Q_LO + ((size_t)bb * 1024 + mq * 32) * 128;
        int row = t >> 4;
        int k8  = (t & 15) * 8;
        *(u32x4*)(Qh + row * 136 + k8) = *(const u32x4*)(qhp + (size_t)row * 128 + k8);
        *(u32x4*)(Ql + row * 136 + k8) = *(const u32x4*)(qlp + (size_t)row * 128 + k8);
    }
    __syncthreads();   // Q visible (also drains early K stages; pipeline restarts below)

    f32x4 acc[8][2] = {};

#pragma unroll
    for (int kc = 0; kc < 4; ++kc) {
        bf16x8 ah = *(const bf16x8*)(Qh + (mt * 16 + lm) * 136 + kc * 32 + q * 8);
        bf16x8 al = *(const bf16x8*)(Ql + (mt * 16 + lm) * 136 + kc * 32 + q * 8);
#pragma unroll
        for (int c = 0; c < 8; ++c) {
            const int s = kc * 8 + c;
            if (s < 31) asm volatile("s_waitcnt vmcnt(2) lgkmcnt(0)" ::: "memory");
            else        asm volatile("s_waitcnt vmcnt(0) lgkmcnt(0)" ::: "memory");
            __builtin_amdgcn_s_barrier();
            if (s + 2 < 32) KSTAGE(s + 2);
            __builtin_amdgcn_sched_barrier(0);
            const bf16* kb = arena + (s % 3) * 8192;
#pragma unroll
            for (int nt = 0; nt < 2; ++nt) {
                bf16x8 bh = *(const bf16x8*)(kb + (kt4 * 32 + nt * 16 + lm) * 32 + q * 8);
                bf16x8 bl = *(const bf16x8*)(kb + 4096 + (kt4 * 32 + nt * 16 + lm) * 32 + q * 8);
                acc[c][nt] = __builtin_amdgcn_mfma_f32_16x16x32_bf16(ah, bh, acc[c][nt], 0, 0, 0);
                acc[c][nt] = __builtin_amdgcn_mfma_f32_16x16x32_bf16(ah, bl, acc[c][nt], 0, 0, 0);
                acc[c][nt] = __builtin_amdgcn_mfma_f32_16x16x32_bf16(al, bh, acc[c][nt], 0, 0, 0);
            }
        }
    }

    // ---- row max (wave-local over its 16 key-tiles, then lm lanes)
#pragma unroll
    for (int r = 0; r < 4; ++r) {
        float m = acc[0][0][r];
#pragma unroll
        for (int c = 0; c < 8; ++c)
#pragma unroll
            for (int nt = 0; nt < 2; ++nt)
                m = fmaxf(m, acc[c][nt][r]);
        m = fmaxf(m, __shfl_xor(m, 1));
        m = fmaxf(m, __shfl_xor(m, 2));
        m = fmaxf(m, __shfl_xor(m, 4));
        m = fmaxf(m, __shfl_xor(m, 8));
        if (lm == 0) red[w][mt * 16 + q * 4 + r] = m;
    }
    __syncthreads();
    if (t < 32) {
        int p = t >> 4;   // rows 0..15 held by even waves, 16..31 by odd
        float m = fmaxf(fmaxf(red[p][t], red[p + 2][t]),
                        fmaxf(red[p + 4][t], red[p + 6][t]));
        rstat[t] = m;
    }
    __syncthreads();

    // ---- exp + row sum
#pragma unroll
    for (int r = 0; r < 4; ++r) {
        float rm = rstat[mt * 16 + q * 4 + r];
        float sum = 0.f;
#pragma unroll
        for (int c = 0; c < 8; ++c)
#pragma unroll
            for (int nt = 0; nt < 2; ++nt) {
                float e = exp2f((acc[c][nt][r] - rm) * LOG2E);
                acc[c][nt][r] = e;
                sum += e;
            }
        sum += __shfl_xor(sum, 1);
        sum += __shfl_xor(sum, 2);
        sum += __shfl_xor(sum, 4);
        sum += __shfl_xor(sum, 8);
        if (lm == 0) red[w][mt * 16 + q * 4 + r] = sum;
    }
    __syncthreads();
    if (t < 32) {
        int p = t >> 4;
        float s2 = red[p][t] + red[p + 2][t] + red[p + 4][t] + red[p + 6][t];
        rstat[t] = 1.0f / s2;
    }
    __syncthreads();

    // ---- normalize fully in registers
#pragma unroll
    for (int r = 0; r < 4; ++r) {
        float inv = rstat[mt * 16 + q * 4 + r];
#pragma unroll
        for (int c = 0; c < 8; ++c)
#pragma unroll
            for (int nt = 0; nt < 2; ++nt)
                acc[c][nt][r] *= inv;
    }

    // ---- PV with staged V (3-buffer ring, depth-2)
    const bf16* gv = ws + VT_OFF + (size_t)bb * 131072
                     + (size_t)(w * 16 + (l >> 2)) * 1024 + (l & 3) * 8;

#define VSTAGE(s)                                                              \
    do {                                                                       \
        GLL16(gv + ((s) >> 4) * 512 + ((s) & 15) * 32,                         \
              arena + 16512 + ((s) % 3) * 4096 + w * 512);                     \
    } while (0)

#define PSCATTER(g)                                                            \
    do {                                                                       \
        _Pragma("unroll")                                                      \
        for (int c4 = 0; c4 < 4; ++c4) {                                       \
            _Pragma("unroll")                                                  \
            for (int nt = 0; nt < 2; ++nt)                                     \
                _Pragma("unroll")                                              \
                for (int r = 0; r < 4; ++r)                                    \
                    arena[(mt * 16 + q * 4 + r) * 516 + c4 * 128 +             \
                          kt4 * 32 + nt * 16 + lm] =                           \
                        (bf16)acc[4 * (g) + c4][nt][r];                        \
        }                                                                      \
    } while (0)

    VSTAGE(0);
    VSTAGE(1);
    // all K-region reads completed before the softmax barriers above ->
    // safe to overlay P onto arena[0,16512)
    PSCATTER(0);
    __syncthreads();

    f32x4 acco[2] = {};
#pragma unroll
    for (int s2 = 0; s2 < 32; ++s2) {
        if (s2 == 16) {
            __syncthreads();      // all P(g=0) reads done
            PSCATTER(1);
            __syncthreads();      // P(g=1) visible (drains vmem too; safe)
        }
        if (s2 < 31) asm volatile("s_waitcnt vmcnt(1) lgkmcnt(0)" ::: "memory");
        else         asm volatile("s_waitcnt vmcnt(0) lgkmcnt(0)" ::: "memory");
        __builtin_amdgcn_s_barrier();
        if (s2 + 2 < 32) VSTAGE(s2 + 2);
        __builtin_amdgcn_sched_barrier(0);
        const bf16* vbp = arena + 16512 + (s2 % 3) * 4096;
        bf16x8 vb = *(const bf16x8*)(vbp + (w * 16 + lm) * 32 + q * 8);
        const int c2 = s2 & 15;
#pragma unroll
        for (int m2 = 0; m2 < 2; ++m2) {
            bf16x8 ap = *(const bf16x8*)(arena + (m2 * 16 + lm) * 516 + c2 * 32 + q * 8);
            acco[m2] = __builtin_amdgcn_mfma_f32_16x16x32_bf16(ap, vb, acco[m2], 0, 0, 0);
        }
    }

    // ---- tail: probs fp32 stores (fire-and-forget, drain at endpgm) + out
    float* pout = out + POFF + (size_t)bb * 1048576;
#pragma unroll
    for (int c = 0; c < 8; ++c)
#pragma unroll
        for (int nt = 0; nt < 2; ++nt)
#pragma unroll
            for (int r = 0; r < 4; ++r) {
                int row = mq * 32 + mt * 16 + q * 4 + r;
                int col = c * 128 + kt4 * 32 + nt * 16 + lm;
                pout[(size_t)row * 1024 + col] = acc[c][nt][r];
            }
#pragma unroll
    for (int m2 = 0; m2 < 2; ++m2)
#pragma unroll
        for (int r = 0; r < 4; ++r) {
            int row = mq * 32 + m2 * 16 + 4 * q + r;
            out[((size_t)bb * 1024 + row) * 128 + w * 16 + lm] = acco[m2][r];
        }
#undef KSTAGE
#undef VSTAGE
#undef PSCATTER
}

// ---------------------------------------------------------------------------
extern "C" void kernel_launch(void* const* d_in, const int* in_sizes, int n_in,
                              void* d_out, int out_size, void* d_ws, size_t ws_size,
                              hipStream_t stream) {
    const float* X  = (const float*)d_in[0];
    const float* Wq = (const float*)d_in[1];
    const float* bq = (const float*)d_in[2];
    const float* Wk = (const float*)d_in[3];
    const float* bk = (const float*)d_in[4];
    const float* Wv = (const float*)d_in[5];
    const float* bv = (const float*)d_in[6];
    float* out = (float*)d_out;
    bf16* ws   = (bf16*)d_ws;

    prep_w<<<48, 256, 0, stream>>>(Wq, Wk, Wv, ws);
    qkv_gemm<<<768, 256, 0, stream>>>(X, bq, bk, bv, ws);
    attn_fused<<<1024, 512, 0, stream>>>(ws, out);
}